// Round 4
// baseline (494.354 us; speedup 1.0000x reference)
//
#include <hip/hip_runtime.h>
#include <hip/hip_bf16.h>

// GCN: x=emb[ids]; x1=relu(GCNConv(x,W1,b1)); y=Ahat@x1; out[g]=b2+(mean_g y)@W2
// Ahat = sym-normalized adjacency with self loops (norm = dinv[src]*dinv[dst]).
//
// Restructuring:
//  - conv1: rank-17 input -> h1=(emb@W1)[type]; neighbor sum factors through
//    17 type bins: C[i][t]=sum dinv_s over nbrs of type t (edge-parallel scalar
//    atomics), then x1[i]=relu(b1+dinv_i*(C[i]@t1 + dinv_i*t1[ti])) dense.
//    (R3: replaces the latency-chained per-row CSR walk, 137 us.)
//  - conv2: aggregation commutes with @W2 and mean-pool -> pool y, GEMM last.
//    CSR entries carry {src, dinv_src} so the inner loop has no random nd read.
//  - R1: graph counts via binary search on sorted batch (no 64-addr atomics).
//  - R2: x1 stored bf16 (halves the conv2 gather stream), 64 lanes/row.

#define DDIM 128
#define CPAD 20   // C row stride (17 used, padded for 16B-aligned float4 reads)
typedef unsigned int uint;

__device__ __forceinline__ float bflo(uint v) { return __uint_as_float(v << 16); }
__device__ __forceinline__ float bfhi(uint v) { return __uint_as_float(v & 0xffff0000u); }
__device__ __forceinline__ uint packbf(float x, float y) {  // RNE round both
    uint ux = __float_as_uint(x), uy = __float_as_uint(y);
    ux = (ux + 0x7fff + ((ux >> 16) & 1)) >> 16;
    uy = (uy + 0x7fff + ((uy >> 16) & 1)) & 0xffff0000u;
    return ux | uy;
}

__global__ void k_deg(const int* __restrict__ dst, int* __restrict__ deg, int E) {
    int i = blockIdx.x * blockDim.x + threadIdx.x;
    int stride = gridDim.x * blockDim.x;
    for (int e = i; e < E; e += stride) atomicAdd(&deg[dst[e]], 1);
}

// batch is sorted: cnt[g] = lower_bound(g+1) - lower_bound(g). No atomics.
__global__ void k_cnt(const int* __restrict__ batch, int* __restrict__ cnt,
                      int N, int G) {
    int g = threadIdx.x;
    if (g >= G) return;
    auto lb = [&](int key) {
        int lo = 0, hi = N;
        while (lo < hi) {
            int mid = (lo + hi) >> 1;
            if (batch[mid] < key) lo = mid + 1; else hi = mid;
        }
        return lo;
    };
    cnt[g] = lb(g + 1) - lb(g);
}

// nd[i] = {dinv_i, type_i bits}; deg is edge-only indegree, +1 self loop.
__global__ void k_pack(const int* __restrict__ deg, const int* __restrict__ ids,
                       float2* __restrict__ nd, int N) {
    int i = blockIdx.x * blockDim.x + threadIdx.x;
    if (i < N) {
        float dinv = rsqrtf((float)(deg[i] + 1));
        nd[i] = make_float2(dinv, __int_as_float(ids[i]));
    }
}

// ---- 3-kernel exclusive scan of deg -> rowStart ----
__global__ void k_scan1(const int* __restrict__ deg, int* __restrict__ rowStart,
                        int* __restrict__ blockSums, int N) {
    __shared__ int sm[1024];
    int t = threadIdx.x, i = blockIdx.x * 1024 + t;
    int v = (i < N) ? deg[i] : 0;
    sm[t] = v; __syncthreads();
    for (int off = 1; off < 1024; off <<= 1) {
        int a = (t >= off) ? sm[t - off] : 0;
        __syncthreads();
        sm[t] += a; __syncthreads();
    }
    int incl = sm[t];
    if (i < N) rowStart[i] = incl - v;
    if (t == 1023) blockSums[blockIdx.x] = incl;
}

__global__ void k_scan2(int* __restrict__ blockSums, int* __restrict__ blockOff, int nb) {
    __shared__ int sm[256];
    int t = threadIdx.x;
    int v = (t < nb) ? blockSums[t] : 0;
    sm[t] = v; __syncthreads();
    for (int off = 1; off < 256; off <<= 1) {
        int a = (t >= off) ? sm[t - off] : 0;
        __syncthreads();
        sm[t] += a; __syncthreads();
    }
    if (t < nb) blockOff[t] = sm[t] - v;
}

__global__ void k_scan3(int* __restrict__ rowStart, const int* __restrict__ blockOff,
                        int N, int E) {
    int t = threadIdx.x, i = blockIdx.x * 1024 + t;
    if (i < N) rowStart[i] += blockOff[blockIdx.x];
    if (i == 0) rowStart[N] = E;
}

// CSR fill; entry = {src bits, dinv_src} so conv2 needs no random nd read.
__global__ void k_fill(const int* __restrict__ src, const int* __restrict__ dst,
                       const int* __restrict__ rowStart, int* __restrict__ cursor,
                       const float2* __restrict__ nd, float2* __restrict__ csrW, int E) {
    int i = blockIdx.x * blockDim.x + threadIdx.x;
    int stride = gridDim.x * blockDim.x;
    for (int e = i; e < E; e += stride) {
        int d = dst[e];
        int s = src[e];
        float ds = nd[s].x;
        int p = atomicAdd(&cursor[d], 1);
        csrW[rowStart[d] + p] = make_float2(__int_as_float(s), ds);
    }
}

// C[dst][type_src] += dinv_src  (edge-parallel, scalar fp32 atomics over 8 MB)
__global__ void k_bin(const int* __restrict__ src, const int* __restrict__ dst,
                      const float2* __restrict__ nd, float* __restrict__ C, int E) {
    int i = blockIdx.x * blockDim.x + threadIdx.x;
    int stride = gridDim.x * blockDim.x;
    for (int e = i; e < E; e += stride) {
        int s = src[e];
        int d = dst[e];
        float2 ns = nd[s];
        atomicAdd(&C[d * CPAD + __float_as_int(ns.y)], ns.x);
    }
}

// t1 = emb @ W1  (17 x 128)
__global__ void k_t1(const float* __restrict__ emb, const float* __restrict__ W1,
                     float* __restrict__ t1) {
    int t = blockIdx.x, f = threadIdx.x;
    float acc = 0.f;
    for (int k = 0; k < DDIM; k++) acc += emb[t * DDIM + k] * W1[k * DDIM + f];
    t1[t * DDIM + f] = acc;
}

// x1[i] = relu(b1 + dinv_i*(sum_t C[i][t]*t1[t] + dinv_i*t1[ti]))  -> bf16x2
// 64 lanes per row (2 features each), 4 waves/block.
__global__ void __launch_bounds__(256) k_x1(
        const float2* __restrict__ nd, const float* __restrict__ C,
        const float* __restrict__ t1, const float* __restrict__ b1,
        uint* __restrict__ x1u, int N) {
    int lane = threadIdx.x & 63, wave = threadIdx.x >> 6;
    int i = blockIdx.x * 4 + wave;
    if (i >= N) return;
    const float2* t1v = (const float2*)t1;
    float2 ndi = nd[i];
    float dinv_i = ndi.x;
    int ti = __float_as_int(ndi.y);
    const float4* Cv = (const float4*)(C + i * CPAD);
    float4 c0 = Cv[0], c1 = Cv[1], c2 = Cv[2], c3 = Cv[3];
    float c16 = C[i * CPAD + 16];
    float cc[17] = {c0.x, c0.y, c0.z, c0.w, c1.x, c1.y, c1.z, c1.w,
                    c2.x, c2.y, c2.z, c2.w, c3.x, c3.y, c3.z, c3.w, c16};
    float2 ts = t1v[ti * 64 + lane];
    float2 acc = make_float2(dinv_i * ts.x, dinv_i * ts.y);  // self loop
#pragma unroll
    for (int t = 0; t < 17; t++) {
        float2 u = t1v[t * 64 + lane];
        acc.x += cc[t] * u.x;
        acc.y += cc[t] * u.y;
    }
    float2 b = ((const float2*)b1)[lane];
    float vx = b.x + dinv_i * acc.x;
    float vy = b.y + dinv_i * acc.y;
    vx = vx > 0.f ? vx : 0.f;
    vy = vy > 0.f ? vy : 0.f;
    x1u[i * 64 + lane] = packbf(vx, vy);
}

// y[i] = dinv_i*(sum_e dinv_s*x1[s] + dinv_i*x1[i]); poolY[batch[i]] += y[i]
// 64 lanes/row (bf16x2 per lane), 4 waves/block, NB rows per wave.
#define NB 16
__global__ void __launch_bounds__(256) k_conv2(
        const float2* __restrict__ nd, const int* __restrict__ rowStart,
        const float2* __restrict__ csrW, const uint* __restrict__ x1u,
        const int* __restrict__ batch, float* __restrict__ poolY, int N) {
    int lane = threadIdx.x & 63, wave = threadIdx.x >> 6;
    int i0 = (blockIdx.x * 4 + wave) * NB;
    if (i0 >= N) return;
    int iend = i0 + NB; if (iend > N) iend = N;
    float2 poolAcc = make_float2(0.f, 0.f);
    int curG = batch[i0];
    for (int i = i0; i < iend; i++) {
        int g = batch[i];
        if (g != curG) {
            atomicAdd(&poolY[curG * DDIM + 2 * lane],     poolAcc.x);
            atomicAdd(&poolY[curG * DDIM + 2 * lane + 1], poolAcc.y);
            poolAcc = make_float2(0.f, 0.f); curG = g;
        }
        float dinv_i = nd[i].x;
        uint self = x1u[i * 64 + lane];
        float2 acc = make_float2(dinv_i * bflo(self), dinv_i * bfhi(self));
        int e0 = rowStart[i], e1 = rowStart[i + 1];
        int e = e0;
        for (; e + 7 < e1; e += 8) {          // 8-wide for memory-level parallelism
            float2 r0 = csrW[e],     r1 = csrW[e + 1], r2 = csrW[e + 2], r3 = csrW[e + 3];
            float2 r4 = csrW[e + 4], r5 = csrW[e + 5], r6 = csrW[e + 6], r7 = csrW[e + 7];
            uint v0 = x1u[__float_as_int(r0.x) * 64 + lane];
            uint v1 = x1u[__float_as_int(r1.x) * 64 + lane];
            uint v2 = x1u[__float_as_int(r2.x) * 64 + lane];
            uint v3 = x1u[__float_as_int(r3.x) * 64 + lane];
            uint v4 = x1u[__float_as_int(r4.x) * 64 + lane];
            uint v5 = x1u[__float_as_int(r5.x) * 64 + lane];
            uint v6 = x1u[__float_as_int(r6.x) * 64 + lane];
            uint v7 = x1u[__float_as_int(r7.x) * 64 + lane];
            acc.x += r0.y * bflo(v0) + r1.y * bflo(v1) + r2.y * bflo(v2) + r3.y * bflo(v3)
                   + r4.y * bflo(v4) + r5.y * bflo(v5) + r6.y * bflo(v6) + r7.y * bflo(v7);
            acc.y += r0.y * bfhi(v0) + r1.y * bfhi(v1) + r2.y * bfhi(v2) + r3.y * bfhi(v3)
                   + r4.y * bfhi(v4) + r5.y * bfhi(v5) + r6.y * bfhi(v6) + r7.y * bfhi(v7);
        }
        for (; e < e1; e++) {
            float2 r = csrW[e];
            uint v = x1u[__float_as_int(r.x) * 64 + lane];
            acc.x += r.y * bflo(v);
            acc.y += r.y * bfhi(v);
        }
        poolAcc.x += dinv_i * acc.x;
        poolAcc.y += dinv_i * acc.y;
    }
    atomicAdd(&poolY[curG * DDIM + 2 * lane],     poolAcc.x);
    atomicAdd(&poolY[curG * DDIM + 2 * lane + 1], poolAcc.y);
}

// out[g] = b2 + (poolY[g]/cnt[g]) @ W2 ; cnt==0 -> 0
__global__ void k_out(const float* __restrict__ poolY, const int* __restrict__ cnt,
                      const float* __restrict__ W2, const float* __restrict__ b2,
                      float* __restrict__ out) {
    int g = blockIdx.x, f = threadIdx.x;
    float acc = 0.f;
    for (int k = 0; k < DDIM; k++) acc += poolY[g * DDIM + k] * W2[k * DDIM + f];
    int c = cnt[g];
    out[g * DDIM + f] = (c > 0) ? (b2[f] + acc / (float)c) : 0.f;
}

extern "C" void kernel_launch(void* const* d_in, const int* in_sizes, int n_in,
                              void* d_out, int out_size, void* d_ws, size_t ws_size,
                              hipStream_t stream) {
    const int* node_ids = (const int*)d_in[0];
    const int* edge_index = (const int*)d_in[1];
    const int* batch = (const int*)d_in[2];
    const float* emb = (const float*)d_in[4];
    const float* W1 = (const float*)d_in[5];
    const float* b1 = (const float*)d_in[6];
    const float* W2 = (const float*)d_in[7];
    const float* b2 = (const float*)d_in[8];
    float* out = (float*)d_out;

    const int N = in_sizes[0];
    const int E = in_sizes[1] / 2;
    const int G = out_size / DDIM;
    const int* src = edge_index;
    const int* dst = edge_index + E;

    char* ws = (char*)d_ws;
    size_t off = 0;
    auto carve = [&](size_t bytes) { char* p = ws + off; off = (off + bytes + 255) & ~size_t(255); return p; };
    uint*   x1u      = (uint*)carve((size_t)N * 64 * 4);      // bf16x2 packed
    float2* csrW     = (float2*)carve((size_t)E * 8);         // {src bits, dinv_src}
    float*  C        = (float*)carve((size_t)N * CPAD * 4);   // type bins
    float2* nd       = (float2*)carve((size_t)N * 8);
    int*    deg      = (int*)carve((size_t)N * 4);
    int*    rowStart = (int*)carve((size_t)(N + 1) * 4);
    int*    cursor   = (int*)carve((size_t)N * 4);
    int*    blockSums= (int*)carve(1024);
    int*    blockOff = (int*)carve(1024);
    float*  t1       = (float*)carve(17 * DDIM * 4);
    float*  poolY    = (float*)carve((size_t)G * DDIM * 4);
    int*    cnt      = (int*)carve((size_t)G * 4);

    hipMemsetAsync(deg,    0, (size_t)N * 4, stream);
    hipMemsetAsync(cursor, 0, (size_t)N * 4, stream);
    hipMemsetAsync(C,      0, (size_t)N * CPAD * 4, stream);
    hipMemsetAsync(poolY,  0, (size_t)G * DDIM * 4, stream);

    k_deg<<<2048, 256, 0, stream>>>(dst, deg, E);
    k_cnt<<<1, 64, 0, stream>>>(batch, cnt, N, G);

    int nb = (N + 1023) / 1024;
    k_scan1<<<nb, 1024, 0, stream>>>(deg, rowStart, blockSums, N);
    k_scan2<<<1, 256, 0, stream>>>(blockSums, blockOff, nb);
    k_scan3<<<nb, 1024, 0, stream>>>(rowStart, blockOff, N, E);

    k_pack<<<(N + 255) / 256, 256, 0, stream>>>(deg, node_ids, nd, N);
    k_fill<<<2048, 256, 0, stream>>>(src, dst, rowStart, cursor, nd, csrW, E);
    k_bin<<<2048, 256, 0, stream>>>(src, dst, nd, C, E);

    k_t1<<<17, DDIM, 0, stream>>>(emb, W1, t1);
    k_x1<<<(N + 3) / 4, 256, 0, stream>>>(nd, C, t1, b1, x1u, N);
    k_conv2<<<(N + 4 * NB - 1) / (4 * NB), 256, 0, stream>>>(nd, rowStart, csrW, x1u, batch, poolY, N);
    k_out<<<G, DDIM, 0, stream>>>(poolY, cnt, W2, b2, out);
}